// Round 2
// 168.132 us; speedup vs baseline: 1.0229x; 1.0229x over previous
//
#include <hip/hip_runtime.h>
#include <math.h>

#define BATCH 2
#define LSEQ  2048
#define DIMM  1024
#define NH    16
#define DH    64

typedef unsigned short ushortT;
typedef __attribute__((ext_vector_type(8))) short bf16x8;
typedef __attribute__((ext_vector_type(4))) float f32x4;

#define MFMA16(a, b, c) __builtin_amdgcn_mfma_f32_16x16x32_bf16((a), (b), (c), 0, 0, 0)

// scale folded into q columns of W_qkv: (1/sqrt(64)) * log2(e)
#define QSCALE 0.18033688011112042f

__device__ __forceinline__ ushortT f2bf(float f) {
    unsigned u = __float_as_uint(f);
    u += 0x7fffu + ((u >> 16) & 1u);   // RNE
    return (ushortT)(u >> 16);
}

// async global->LDS, 16B per lane. LDS dest is wave-uniform base + lane*16.
// NOTE (R8 lesson): register-prefetch staging spills to scratch (WRITE_SIZE
// 10x output, VGPR stays ~112) — keep DMA staging.
__device__ __forceinline__ void gll16(const ushortT* g, ushortT* l) {
    ushortT* gm = const_cast<ushortT*>(g);
    __builtin_amdgcn_global_load_lds(
        (__attribute__((address_space(1))) void*)gm,
        (__attribute__((address_space(3))) void*)l, 16, 0, 0);
}

// ---------------------------------------------------------------------------
// Fused prep: blocks [0,4096): x fp32->bf16; blocks [4096,8192): weight
// transposes W[K][N] fp32 -> Wt[N][K] bf16 (q-cols of W_qkv scaled by QSCALE).
// ---------------------------------------------------------------------------
__global__ __launch_bounds__(256) void prep(
    const float* __restrict__ x, ushortT* __restrict__ xb,
    const float* __restrict__ Wqkv, const float* __restrict__ Wout,
    ushortT* __restrict__ wqt, ushortT* __restrict__ wot)
{
    __shared__ float T[32][33];
    const int bx = blockIdx.x;
    const int tid = threadIdx.x;
    if (bx < 4096) {
        int i = bx * 256 + tid;
        float4 v = ((const float4*)x)[i];
        ushort4 o;
        o.x = f2bf(v.x); o.y = f2bf(v.y); o.z = f2bf(v.z); o.w = f2bf(v.w);
        ((ushort4*)xb)[i] = o;
        return;
    }
    const int id2 = bx - 4096;
    const int nb = id2 & 127, kb = id2 >> 7;
    const float* W; ushortT* Wt; int N, n0, nlimit;
    if (nb < 96) { W = Wqkv; Wt = wqt; N = 3 * DIMM; n0 = nb * 32; nlimit = DIMM; }
    else         { W = Wout; Wt = wot; N = DIMM;     n0 = (nb - 96) * 32; nlimit = 0; }
    const int k0 = kb * 32;
    const int c = tid & 31, r0 = tid >> 5;
#pragma unroll
    for (int p = 0; p < 4; ++p)
        T[r0 + 8 * p][c] = W[(size_t)(k0 + r0 + 8 * p) * N + n0 + c];
    __syncthreads();
#pragma unroll
    for (int p = 0; p < 4; ++p) {
        int rr = r0 + 8 * p;
        float v = T[c][rr];
        if (n0 + rr < nlimit) v *= QSCALE;
        Wt[(size_t)(n0 + rr) * DIMM + k0 + c] = f2bf(v);
    }
}

// ---------------------------------------------------------------------------
// R11: 256x256 4-phase pipelined mainloop — R10 race FIXED.
// R10 bug: vmcnt(6)/phase only retired 2 of 8 staging loads per tile, but
// every wave reads 2 of the 4 half-tiles already at phase 0 of the consuming
// tile -> read un-landed LDS -> NaN. Fix: issue all staging EARLY (phases
// 0 and 1), single vmcnt(0) drain at end of phase 3 before the tile-boundary
// barrier. Per-wave drain + barrier => all DMA writes LDS-visible before any
// phase-0 ds_read of the next tile. Loads are 2.5-3.5 phases old at the
// drain, so most latency is hidden (deep-issue double-buffer).
// 8 waves (2M x 4N), BK=64, 128 KiB LDS double-buffer, 4 half-tiles/buffer
// (ht0/1 = A rows 0-127/128-255, ht2/3 = B rows 0-127/128-255; each 128x64).
// Phase p: {ds_read frag subtile | stage | barrier | lgkmcnt(0) |
//           setprio(1) 16xMFMA setprio(0) | [p==3: vmcnt(0)] | barrier}.
// SWAP=false: acc rows = A(m); SWAP=true: acc rows = Bt(n) (C^T for q/k).
// Swizzle identical to the proven 128^2 loop (0 bank conflicts measured).
// ---------------------------------------------------------------------------
template<bool SWAP>
__device__ __forceinline__ void mainloop256(
    const ushortT* __restrict__ A, const ushortT* __restrict__ Bt,
    ushortT S[2][4][8192], int bm, int bn, int w, int lane, f32x4 acc[8][4])
{
    const int quad = lane >> 4, li = lane & 15;
    const int wm = w >> 2, wn = w & 3;
    const int sw = li & 7;
    const int s0 = (quad ^ sw) * 8, s1 = ((quad + 4) ^ sw) * 8;
    const int r8 = lane >> 3, c8 = lane & 7, cch = c8 ^ r8;
    const ushortT* sA = A  + (size_t)(bm + 16 * w + r8) * DIMM + cch * 8;
    const ushortT* sB = Bt + (size_t)(bn + 16 * w + r8) * DIMM + cch * 8;
    const int RSht = SWAP ? 2 + wm : wm;          // row-operand half-tile
    const int CSht = SWAP ? (wn >> 1) : 2 + (wn >> 1);  // col-operand half-tile
    const int cb64 = (wn & 1) * 64;               // row base within CS half-tile
    bf16x8 af[4][2], bfr[4][2];
    int koff = 0;

#define STAGE_HT(P) do { \
        const ushortT* sp_ = (((P) < 2) ? sA : sB) + ((P) & 1) * 128 * DIMM + koff; \
        gll16(sp_,            &Snext[(P)][(16 * w) * 64]); \
        gll16(sp_ + 8 * DIMM, &Snext[(P)][(16 * w + 8) * 64]); \
    } while (0)

    {   // prologue: stage K-tile 0 into S[0], full drain
        ushortT (*Snext)[8192] = S[0];
        STAGE_HT(0); STAGE_HT(1); STAGE_HT(2); STAGE_HT(3);
        __syncthreads();   // vmcnt(0) lgkmcnt(0) + barrier
    }
    koff = 64;

#define PHASE(P, STG) do { \
        if ((P) == 0 || (P) == 2) { \
            const int rh_ = ((P) == 2) ? 64 : 0; \
            _Pragma("unroll") \
            for (int rt_ = 0; rt_ < 4; ++rt_) { \
                const int R_ = rh_ + 16 * rt_ + li; \
                af[rt_][0] = *(const bf16x8*)&RS[R_ * 64 + s0]; \
                af[rt_][1] = *(const bf16x8*)&RS[R_ * 64 + s1]; \
            } \
        } \
        if ((P) == 0 || (P) == 1) { \
            _Pragma("unroll") \
            for (int c_ = 0; c_ < 2; ++c_) { \
                const int ct_ = (P) * 2 + c_; \
                const int R_ = cb64 + 16 * ct_ + li; \
                bfr[ct_][0] = *(const bf16x8*)&CS[R_ * 64 + s0]; \
                bfr[ct_][1] = *(const bf16x8*)&CS[R_ * 64 + s1]; \
            } \
        } \
        if (STG) { \
            if ((P) == 0) { STAGE_HT(0); STAGE_HT(1); } \
            if ((P) == 1) { STAGE_HT(2); STAGE_HT(3); } \
        } \
        __builtin_amdgcn_s_barrier(); \
        asm volatile("s_waitcnt lgkmcnt(0)" ::: "memory"); \
        __builtin_amdgcn_sched_barrier(0); \
        __builtin_amdgcn_s_setprio(1); \
        { \
            const int rb_ = ((P) >= 2) ? 4 : 0; \
            const int cb_ = ((P) == 1 || (P) == 2) ? 2 : 0; \
            _Pragma("unroll") \
            for (int rt_ = 0; rt_ < 4; ++rt_) { \
                _Pragma("unroll") \
                for (int c_ = 0; c_ < 2; ++c_) { \
                    acc[rb_ + rt_][cb_ + c_] = MFMA16(af[rt_][0], bfr[cb_ + c_][0], acc[rb_ + rt_][cb_ + c_]); \
                    acc[rb_ + rt_][cb_ + c_] = MFMA16(af[rt_][1], bfr[cb_ + c_][1], acc[rb_ + rt_][cb_ + c_]); \
                } \
            } \
        } \
        __builtin_amdgcn_s_setprio(0); \
        if ((STG) && (P) == 3) { asm volatile("s_waitcnt vmcnt(0)" ::: "memory"); } \
        __builtin_amdgcn_sched_barrier(0); \
        __builtin_amdgcn_s_barrier(); \
    } while (0)

#define KTILE(CUR, NXT, STG) do { \
        const ushortT* RS = &S[CUR][RSht][0]; \
        const ushortT* CS = &S[CUR][CSht][0]; \
        ushortT (*Snext)[8192] = S[NXT]; (void)Snext; \
        PHASE(0, STG); PHASE(1, STG); PHASE(2, STG); PHASE(3, STG); \
        koff += 64; \
    } while (0)

    // K = 1024 -> 16 K-tiles; kt parity picks buffer; stage kt+1 while
    // computing kt (drained at end of each staging tile). Last tile peeled.
#pragma unroll 1
    for (int it = 0; it < 7; ++it) { KTILE(0, 1, 1); KTILE(1, 0, 1); }
    KTILE(0, 1, 1);                                     // kt = 14 (drains kt15)
    KTILE(1, 0, 0);                                     // kt = 15
#undef KTILE
#undef PHASE
#undef STAGE_HT
}

// ---------------------------------------------------------------------------
// GEMM1: qkv projection, 256^2 tiles, 512 threads, 192 blocks (1/CU).
// q/k via swapped mainloop -> vectorized [b,h,l,d] stores; v via normal
// mainloop -> vectorized transposed [b,h,d,l] stores.
// ---------------------------------------------------------------------------
__global__ __launch_bounds__(512, 2) void gemm_qkv(
    const ushortT* __restrict__ A, const ushortT* __restrict__ Bt,
    const float* __restrict__ bias,
    ushortT* __restrict__ qb, ushortT* __restrict__ kb, ushortT* __restrict__ vt)
{
    __shared__ __align__(16) ushortT S[2][4][8192];   // 128 KiB
    const int tid = threadIdx.x;
    const int w = tid >> 6, lane = tid & 63, quad = lane >> 4, li = lane & 15;
    const int wm = w >> 2, wn = w & 3;
    // bijective XCD swizzle (192 % 8 == 0): each XCD gets 24 consecutive
    // tiles = 2 full M-panels -> A-panel L2 reuse.
    const int bid = blockIdx.x;
    const int nbid = (bid & 7) * 24 + (bid >> 3);
    const int bx = nbid % 12, by = nbid / 12;
    const int bm = by * 256, bn = bx * 256;
    const int which = bx >> 2;                        // 0=q 1=k 2=v (uniform)
    const f32x4 z4 = {0.f, 0.f, 0.f, 0.f};
    f32x4 acc[8][4];
#pragma unroll
    for (int i = 0; i < 8; ++i)
#pragma unroll
        for (int j = 0; j < 4; ++j) acc[i][j] = z4;

    if (which == 2) {
        mainloop256<false>(A, Bt, S, bm, bn, w, lane, acc);
#pragma unroll
        for (int rt = 0; rt < 8; ++rt) {
            const int m = bm + wm * 128 + (rt >> 2) * 64 + (rt & 3) * 16 + quad * 4;
            const int b = m >> 11, l = m & 2047;
#pragma unroll
            for (int ct = 0; ct < 4; ++ct) {
                const int n = bn + wn * 64 + 16 * ct + li;
                const int nn = n & 1023;
                const int h = nn >> 6, dd = nn & 63;
                const float bterm = bias[n];
                ushort4 o4;
                o4.x = f2bf(acc[rt][ct][0] + bterm);
                o4.y = f2bf(acc[rt][ct][1] + bterm);
                o4.z = f2bf(acc[rt][ct][2] + bterm);
                o4.w = f2bf(acc[rt][ct][3] + bterm);
                *(ushort4*)(vt + ((size_t)(b * NH + h) * DH + dd) * LSEQ + l) = o4;
            }
        }
    } else {
        mainloop256<true>(A, Bt, S, bm, bn, w, lane, acc);
        const float bscale = (which == 0) ? QSCALE : 1.0f;
        ushortT* dst = (which == 0) ? qb : kb;
#pragma unroll
        for (int rt = 0; rt < 8; ++rt) {
            const int n0 = bn + wm * 128 + (rt >> 2) * 64 + (rt & 3) * 16 + quad * 4;
            const int nn0 = n0 & 1023;
            const int h = nn0 >> 6, dd = nn0 & 63;
            const float4 bv = *(const float4*)&bias[n0];
#pragma unroll
            for (int ct = 0; ct < 4; ++ct) {
                const int m = bm + wn * 64 + 16 * ct + li;
                const int b = m >> 11, l = m & 2047;
                ushort4 o4;
                o4.x = f2bf(acc[rt][ct][0] + bv.x * bscale);
                o4.y = f2bf(acc[rt][ct][1] + bv.y * bscale);
                o4.z = f2bf(acc[rt][ct][2] + bv.z * bscale);
                o4.w = f2bf(acc[rt][ct][3] + bv.w * bscale);
                *(ushort4*)(dst + ((size_t)(b * NH + h) * LSEQ + l) * DH + dd) = o4;
            }
        }
    }
}

// ---------------------------------------------------------------------------
// GEMM2: out = o @ W_out + b_out (fp32 out). 128(M)x64(N) tiles, BK=128,
// DMA staging (R7 version — register prefetch spilled, see R8).
// ---------------------------------------------------------------------------
__global__ __launch_bounds__(256) void gemm_out(
    const ushortT* __restrict__ A, const ushortT* __restrict__ Bt,
    const float* __restrict__ bias, float* __restrict__ out)
{
    __shared__ __align__(16) ushortT As[128 * 128];   // 32 KB
    __shared__ __align__(16) ushortT Bs[64 * 128];    // 16 KB
    const int tid = threadIdx.x;
    const int w = tid >> 6, lane = tid & 63, quad = lane >> 4, li = lane & 15;
    const int bm = blockIdx.y * 128, bn = blockIdx.x * 64;
    const int wm = (w & 1) * 64, wn = (w >> 1) * 32;
    const int r4 = lane >> 4, c16 = lane & 15;
    const int sw = li & 7;

    const ushortT* pa[8]; ushortT* la[8];
#pragma unroll
    for (int j = 0; j < 8; ++j) {
        int Bi = w + 4 * j;
        int row = Bi * 4 + r4;
        int cxA = c16 ^ ((Bi & 1) * 4 + r4);       // == c16 ^ (row&7)
        pa[j] = A + (size_t)(bm + row) * DIMM + cxA * 8;
        la[j] = As + Bi * 512;
    }
    const ushortT* pb[4]; ushortT* lb[4];
#pragma unroll
    for (int j = 0; j < 4; ++j) {
        int Bi = w + 4 * j;
        int row = Bi * 4 + r4;
        int cxB = c16 ^ ((Bi & 1) * 4 + r4);
        pb[j] = Bt + (size_t)(bn + row) * DIMM + cxB * 8;
        lb[j] = Bs + Bi * 512;
    }

    const f32x4 z4 = {0.f, 0.f, 0.f, 0.f};
    f32x4 acc[4][2];
#pragma unroll
    for (int i = 0; i < 4; ++i) { acc[i][0] = z4; acc[i][1] = z4; }

    for (int k0 = 0; k0 < DIMM; k0 += 128) {
#pragma unroll
        for (int j = 0; j < 8; ++j) { gll16(pa[j], la[j]); pa[j] += 128; }
#pragma unroll
        for (int j = 0; j < 4; ++j) { gll16(pb[j], lb[j]); pb[j] += 128; }
        __syncthreads();
#pragma unroll
        for (int g = 0; g < 2; ++g) {
            const int s0 = (g * 8 + (quad ^ sw)) * 8;
            const int s1 = (g * 8 + ((quad + 4) ^ sw)) * 8;
            bf16x8 bfr[2][2];
#pragma unroll
            for (int t = 0; t < 2; ++t) {
                int R = wn + 16 * t + li;
                bfr[t][0] = *(const bf16x8*)&Bs[R * 128 + s0];
                bfr[t][1] = *(const bf16x8*)&Bs[R * 128 + s1];
            }
#pragma unroll
            for (int rt = 0; rt < 4; ++rt) {
                int R = wm + 16 * rt + li;
                bf16x8 a0 = *(const bf16x8*)&As[R * 128 + s0];
                bf16x8 a1 = *(const bf16x8*)&As[R * 128 + s1];
#pragma unroll
                for (int ct = 0; ct < 2; ++ct) {
                    acc[rt][ct] = MFMA16(a0, bfr[ct][0], acc[rt][ct]);
                    acc[rt][ct] = MFMA16(a1, bfr[ct][1], acc[rt][ct]);
                }
            }
        }
        __syncthreads();
    }
#pragma unroll
    for (int rt = 0; rt < 4; ++rt) {
#pragma unroll
        for (int ct = 0; ct < 2; ++ct) {
            int n = bn + wn + 16 * ct + li;
            float bterm = bias[n];
#pragma unroll
            for (int r = 0; r < 4; ++r) {
                int m = bm + wm + 16 * rt + quad * 4 + r;
                out[(size_t)m * DIMM + n] = acc[rt][ct][r] + bterm;
            }
        }
    }
}

// ---------------------------------------------------------------------------
// Flash attention, block-causal, transposed inner math, 128-KEY TILES.
// R9: softmax denominators computed by MFMA (A = ones, B = P^T fragments
// already loaded for PV) — removes the per-element AND+fadd chain and the
// final shuffle reduction; sum is exactly consistent with stored bf16 P.
// P packing via v_perm_b32 (1 op per pair).
// ---------------------------------------------------------------------------
__global__ __launch_bounds__(256, 2) void attn(
    const ushortT* __restrict__ qg, const ushortT* __restrict__ kg,
    const ushortT* __restrict__ vtg, ushortT* __restrict__ og)
{
    __shared__ __align__(16) ushortT Kbuf[2][8192];   // [p][half*4096 + blk*512]
    __shared__ __align__(16) ushortT Vbuf[2][8192];   // [d][l] halves
    __shared__ __align__(16) ushortT PsT[4096];       // 4 waves x 2 KB

    const int tid = threadIdx.x;
    const int w = tid >> 6, lane = tid & 63, quad = lane >> 4, li = lane & 15;
    const int id = blockIdx.x;                 // 0..511
    const int qt = (id < 256) ? (15 - (id >> 5)) : ((id - 256) >> 5);
    const int bhid = id & 31;
    const int b = bhid >> 4, h = bhid & 15;
    const size_t bh = (size_t)b * NH + h;
    const ushortT* qbase = qg + (bh * LSEQ + qt * 128) * DH;
    const ushortT* kbase = kg + bh * LSEQ * DH;
    const ushortT* vbase = vtg + bh * DH * LSEQ;
    ushortT* obase = og + ((size_t)b * LSEQ + qt * 128) * DIMM + h * DH;
    const f32x4 z4 = {0.f, 0.f, 0.f, 0.f};

    // ones A-fragment for the denominator MFMA (bf16 1.0 = 0x3F80)
    const short ONE = (short)0x3F80;
    const bf16x8 onesA = {ONE, ONE, ONE, ONE, ONE, ONE, ONE, ONE};

    // staging lane geometry (within each 8-row x 1KB DMA block)
    const int r8 = lane >> 3, c8 = lane & 7, cx = c8 ^ r8;

    bf16x8 qf[2][2];
#pragma unroll
    for (int band = 0; band < 2; ++band) {
        int row = 32 * w + 16 * band + li;
        qf[band][0] = *(const bf16x8*)(qbase + (size_t)row * DH + quad * 8);
        qf[band][1] = *(const bf16x8*)(qbase + (size_t)row * DH + 32 + quad * 8);
    }
    f32x4 oaccT[2][4];     // [band][dt]: O^T, lane owns qrow=li
    f32x4 lsacc[2];        // denominator acc (all 4 comps equal per lane)
#pragma unroll
    for (int i = 0; i < 2; ++i) {
        lsacc[i] = z4;
#pragma unroll
        for (int j = 0; j < 4; ++j) oaccT[i][j] = z4;
    }

    const int nt = qt + 1;                 // 128-key tiles
    // stage tile 0 (8 gll16/wave: 2 halves x {K,V} x 2 blocks)
#pragma unroll
    for (int s = 0; s < 2; ++s)
#pragma unroll
        for (int jj = 0; jj < 2; ++jj) {
            int B = w + 4 * jj;
            gll16(kbase + (size_t)(s * 64 + B * 8 + r8) * DH + cx * 8,
                  &Kbuf[0][s * 4096 + B * 512]);
            gll16(vbase + (size_t)(B * 8 + r8) * LSEQ + s * 64 + cx * 8,
                  &Vbuf[0][s * 4096 + B * 512]);
        }
    __syncthreads();

    const int sw = li & 7;
    const int pbase = w * 1024 + li * 8;

    for (int t = 0; t < nt; ++t) {
        const int p = t & 1;
        if (t + 1 < nt) {   // DMA next 128-key tile; drains at loop barrier
#pragma unroll
            for (int s = 0; s < 2; ++s)
#pragma unroll
                for (int jj = 0; jj < 2; ++jj) {
                    int B = w + 4 * jj;
                    gll16(kbase + (size_t)((t + 1) * 128 + s * 64 + B * 8 + r8) * DH + cx * 8,
                          &Kbuf[1 - p][s * 4096 + B * 512]);
                    gll16(vbase + (size_t)(B * 8 + r8) * LSEQ + (t + 1) * 128 + s * 64 + cx * 8,
                          &Vbuf[1 - p][s * 4096 + B * 512]);
                }
        }

#pragma unroll
        for (int s = 0; s < 2; ++s) {
            const ushortT* Kb = &Kbuf[p][s * 4096];
            const ushortT* Vb = &Vbuf[p][s * 4096];
            bf16x8 kf[4][2], vf[4][2];
#pragma unroll
            for (int ct = 0; ct < 4; ++ct) {
                int R = 16 * ct + li;
                kf[ct][0] = *(const bf16x8*)&Kb[R * 64 + (quad ^ sw) * 8];
                kf[ct][1] = *(const bf16x8*)&Kb[R * 64 + ((quad + 4) ^ sw) * 8];
            }
#pragma unroll
            for (int dt = 0; dt < 4; ++dt) {
                int R = 16 * dt + li;
                vf[dt][0] = *(const bf16x8*)&Vb[R * 64 + (quad ^ sw) * 8];
                vf[dt][1] = *(const bf16x8*)&Vb[R * 64 + ((quad + 4) ^ sw) * 8];
            }
#pragma unroll
            for (int band = 0; band < 2; ++band) {
                // S^T = K Q^T (pre-scaled, log2 domain)
                f32x4 sa[4];
#pragma unroll
                for (int ct = 0; ct < 4; ++ct) {
                    sa[ct] = MFMA16(kf[ct][0], qf[band][0], z4);
                    sa[ct] = MFMA16(kf[ct][1], qf[band][1], sa[ct]);
                }
                // exp2, pack 4 keys (RTZ bf16) via v_perm, one b64 write
#pragma unroll
                for (int ct = 0; ct < 4; ++ct) {
                    unsigned u0 = __float_as_uint(__builtin_amdgcn_exp2f(sa[ct][0]));
                    unsigned u1 = __float_as_uint(__builtin_amdgcn_exp2f(sa[ct][1]));
                    unsigned u2 = __float_as_uint(__builtin_amdgcn_exp2f(sa[ct][2]));
                    unsigned u3 = __float_as_uint(__builtin_amdgcn_exp2f(sa[ct][3]));
                    uint2 pk;
                    pk.x = __builtin_amdgcn_perm(u1, u0, 0x07060302u);
                    pk.y = __builtin_amdgcn_perm(u3, u2, 0x07060302u);
                    *(uint2*)&PsT[pbase + (2 * ct + (quad >> 1)) * 128 + (quad & 1) * 4] = pk;
                }
                // read P^T fragments once; use for BOTH denominator and PV
                bf16x8 pt0 = *(const bf16x8*)&PsT[pbase + quad * 128];
                bf16x8 pt1 = *(const bf16x8*)&PsT[pbase + (4 + quad) * 128];
                lsacc[band] = MFMA16(onesA, pt0, lsacc[band]);   // denom += col-sums
                lsacc[band] = MFMA16(onesA, pt1, lsacc[band]);
#pragma unroll
                for (int dt = 0; dt < 4; ++dt) {
                    oaccT[band][dt] = MFMA16(vf[dt][0], pt0, oaccT[band][dt]);
                    oaccT[band][dt] = MFMA16(vf[dt][1], pt1, oaccT[band][dt]);
                }
            }
        }
        __syncthreads();   // DMA drained + all readers of buf[p] done
    }

    // ---- normalize (denominator complete per-lane), store O (ushort4 on d) ----
#pragma unroll
    for (int band = 0; band < 2; ++band) {
        float inv = 1.0f / lsacc[band][0];
        int m = 32 * w + 16 * band + li;        // qrow
#pragma unroll
        for (int dt = 0; dt < 4; ++dt) {
            ushort4 o4;
            o4.x = f2bf(oaccT[band][dt][0] * inv);
            o4.y = f2bf(oaccT[band][dt][1] * inv);
            o4.z = f2bf(oaccT[band][dt][2] * inv);
            o4.w = f2bf(oaccT[band][dt][3] * inv);
            *(ushort4*)(obase + (size_t)m * DIMM + 16 * dt + quad * 4) = o4;
        }
    }
}

// ---------------------------------------------------------------------------
extern "C" void kernel_launch(void* const* d_in, const int* in_sizes, int n_in,
                              void* d_out, int out_size, void* d_ws, size_t ws_size,
                              hipStream_t stream)
{
    const float* x    = (const float*)d_in[0];
    const float* Wqkv = (const float*)d_in[1];
    const float* bqkv = (const float*)d_in[2];
    const float* Wout = (const float*)d_in[3];
    const float* bout = (const float*)d_in[4];

    const size_t M4 = (size_t)4 * 1024 * 1024;
    ushortT* ws  = (ushortT*)d_ws;
    ushortT* xb  = ws;                                  // 4M shorts
    ushortT* qb  = ws + M4;                             // 4M
    ushortT* kb  = ws + 2 * M4;                         // 4M
    ushortT* vt  = ws + 3 * M4;                         // 4M  [B,H,d,L]
    ushortT* ob  = ws + 4 * M4;                         // 4M  [B,L,H*d]
    ushortT* wqt = ws + 5 * M4;                         // 3M
    ushortT* wot = ws + 5 * M4 + (size_t)3 * 1024 * 1024;  // 1M

    prep<<<8192, 256, 0, stream>>>(x, xb, Wqkv, Wout, wqt, wot);
    gemm_qkv<<<dim3(192), 512, 0, stream>>>(xb, wqt, bqkv, qb, kb, vt);
    attn<<<dim3(512), 256, 0, stream>>>(qb, kb, vt, ob);
    gemm_out<<<dim3(16, 32), 256, 0, stream>>>(ob, wot, bout, (float*)d_out);
}